// Round 1
// baseline (232.074 us; speedup 1.0000x reference)
//
#include <hip/hip_runtime.h>
#include <hip/hip_bf16.h>
#include <stdint.h>

typedef __bf16 bf16_t;
typedef bf16_t bf16x8 __attribute__((ext_vector_type(8)));
typedef float f32x4 __attribute__((ext_vector_type(4)));

#define BM 128
#define BN 128
#define BK 64

// ---------------------------------------------------------------------------
// async global->LDS 16B copy. LDS dest is wave-uniform base; HW adds lane*16.
// ---------------------------------------------------------------------------
__device__ __forceinline__ void gload_lds16(const void* g, void* l) {
  __builtin_amdgcn_global_load_lds(
      (const __attribute__((address_space(1))) uint32_t*)g,
      (__attribute__((address_space(3))) uint32_t*)l, 16, 0, 0);
}

// ---------------------------------------------------------------------------
// fp32 -> bf16 conversion (x), vectorized 8 elems/thread, grid-stride
// ---------------------------------------------------------------------------
__global__ __launch_bounds__(256) void cvt_x_kernel(
    const float* __restrict__ in, bf16_t* __restrict__ out, int n8) {
  int stride = gridDim.x * blockDim.x;
  for (int i = blockIdx.x * blockDim.x + threadIdx.x; i < n8; i += stride) {
    const f32x4* p = (const f32x4*)in + 2 * (size_t)i;
    f32x4 a = p[0], b = p[1];
    bf16x8 o;
#pragma unroll
    for (int r = 0; r < 4; ++r) { o[r] = (bf16_t)a[r]; o[r + 4] = (bf16_t)b[r]; }
    *((bf16x8*)out + i) = o;
  }
}

// fp32 weight -> bf16 with per-row (output channel) scale folded in
__global__ __launch_bounds__(256) void cvt_w_kernel(
    const float* __restrict__ in, const float* __restrict__ scale,
    bf16_t* __restrict__ out, int k8, int n8) {
  int stride = gridDim.x * blockDim.x;
  for (int i = blockIdx.x * blockDim.x + threadIdx.x; i < n8; i += stride) {
    int row = i / k8;
    float s = scale[row];
    const f32x4* p = (const f32x4*)in + 2 * (size_t)i;
    f32x4 a = p[0], b = p[1];
    bf16x8 o;
#pragma unroll
    for (int r = 0; r < 4; ++r) {
      o[r] = (bf16_t)(a[r] * s);
      o[r + 4] = (bf16_t)(b[r] * s);
    }
    *((bf16x8*)out + i) = o;
  }
}

// ---------------------------------------------------------------------------
// bf16 GEMM, both operands K-major (B^T form). C = A * B^T + bias
// m97 structure: 128x128 tile, BK=64, 4 waves (2x2), 16x16x32 MFMA,
// global_load_lds width 16, single LDS buffer, 2 barriers per K-step.
// ---------------------------------------------------------------------------
__global__ __launch_bounds__(256, 2) void gemm_bt_bf16(
    const bf16_t* __restrict__ A, const bf16_t* __restrict__ B,
    const float* __restrict__ bias, float* __restrict__ C,
    int M, int N, int K) {
  __shared__ bf16_t lA[BM * BK];
  __shared__ bf16_t lB[BN * BK];

  const int tid = threadIdx.x;
  const int lane = tid & 63;
  const int wave = tid >> 6;

  // XCD-aware bijective swizzle (grid is multiple of 8 for 4096^2 / 128^2)
  int nwg = gridDim.x;
  int wg = blockIdx.x;
  if ((nwg & 7) == 0) {
    int cpx = nwg >> 3;
    wg = (wg & 7) * cpx + (wg >> 3);
  }
  const int ntn = N / BN;
  const int tm = wg / ntn;
  const int tn = wg % ntn;

  const int wm = wave >> 1;  // 2x2 wave grid, each wave owns 64x64 output
  const int wn = wave & 1;

  f32x4 acc[4][4];
#pragma unroll
  for (int i = 0; i < 4; ++i)
#pragma unroll
    for (int j = 0; j < 4; ++j) acc[i][j] = (f32x4)0.0f;

  const char* gA = (const char*)(A + (size_t)tm * BM * K);
  const char* gB = (const char*)(B + (size_t)tn * BN * K);
  const size_t rowbytes = (size_t)K * 2;
  char* lAb = (char*)lA;
  char* lBb = (char*)lB;

  // per-thread staging geometry: chunk c covers LDS bytes [c*4096 + tid*16)
  // LDS layout linear [row][col] bf16, row stride BK*2 = 128 bytes.
  const int lbase = wave * 1024;       // wave-uniform LDS base within chunk
  const int off0 = wave * 1024 + lane * 16;

  for (int k0 = 0; k0 < K; k0 += BK) {
#pragma unroll
    for (int c = 0; c < 4; ++c) {
      int off = c * 4096 + off0;
      int row = off >> 7;
      int cb = off & 127;
      gload_lds16(gA + (size_t)row * rowbytes + (size_t)(k0 * 2 + cb),
                  lAb + c * 4096 + lbase);
    }
#pragma unroll
    for (int c = 0; c < 4; ++c) {
      int off = c * 4096 + off0;
      int row = off >> 7;
      int cb = off & 127;
      gload_lds16(gB + (size_t)row * rowbytes + (size_t)(k0 * 2 + cb),
                  lBb + c * 4096 + lbase);
    }
    __syncthreads();  // drains vmcnt before any wave reads LDS

#pragma unroll
    for (int ks = 0; ks < 2; ++ks) {
      bf16x8 af[4], bfr[4];
      const int kb = ks * 64 + ((lane >> 4) << 4);  // byte offset of k-slice
#pragma unroll
      for (int i = 0; i < 4; ++i) {
        int row = wm * 64 + i * 16 + (lane & 15);
        af[i] = *(const bf16x8*)(lAb + row * 128 + kb);
      }
#pragma unroll
      for (int j = 0; j < 4; ++j) {
        int row = wn * 64 + j * 16 + (lane & 15);
        bfr[j] = *(const bf16x8*)(lBb + row * 128 + kb);
      }
#pragma unroll
      for (int i = 0; i < 4; ++i)
#pragma unroll
        for (int j = 0; j < 4; ++j)
          acc[i][j] = __builtin_amdgcn_mfma_f32_16x16x32_bf16(
              af[i], bfr[j], acc[i][j], 0, 0, 0);
    }
    __syncthreads();  // before overwriting LDS next iteration
  }

  // epilogue: C/D layout col = lane&15, row = (lane>>4)*4 + r
  const int row0 = tm * BM + wm * 64;
  const int col0 = tn * BN + wn * 64;
#pragma unroll
  for (int j = 0; j < 4; ++j) {
    int c = col0 + j * 16 + (lane & 15);
    float bv = bias[c];
#pragma unroll
    for (int i = 0; i < 4; ++i) {
      int rbase = row0 + i * 16 + ((lane >> 4) << 2);
#pragma unroll
      for (int r = 0; r < 4; ++r) {
        C[(size_t)(rbase + r) * N + c] = acc[i][j][r] + bv;
      }
    }
  }
}

// ---------------------------------------------------------------------------
// fallback: naive fp32 (only if workspace too small — correctness net)
// ---------------------------------------------------------------------------
__global__ void fallback_gemm(const float* __restrict__ x,
                              const float* __restrict__ w,
                              const float* __restrict__ s,
                              const float* __restrict__ b,
                              float* __restrict__ out, int M, int N, int K) {
  int o = blockIdx.x * blockDim.x + threadIdx.x;
  if (o >= M * N) return;
  int m = o / N, n = o % N;
  const float* xr = x + (size_t)m * K;
  const float* wr = w + (size_t)n * K;
  float acc = 0.f;
  for (int k = 0; k < K; ++k) acc += xr[k] * wr[k];
  out[o] = acc * s[n] + b[n];
}

extern "C" void kernel_launch(void* const* d_in, const int* in_sizes, int n_in,
                              void* d_out, int out_size, void* d_ws,
                              size_t ws_size, hipStream_t stream) {
  const float* x = (const float*)d_in[0];
  const float* w = (const float*)d_in[1];
  const float* sc = (const float*)d_in[2];
  const float* bias = (const float*)d_in[3];
  float* out = (float*)d_out;

  const int N = in_sizes[2];        // out_features (weight_scale length)
  const int K = in_sizes[1] / N;    // in_features
  const int M = in_sizes[0] / K;    // tokens

  const size_t need = ((size_t)M * K + (size_t)N * K) * sizeof(bf16_t);
  const bool fast = (ws_size >= need) && (M % BM == 0) && (N % BN == 0) &&
                    (K % BK == 0);

  if (fast) {
    bf16_t* xb = (bf16_t*)d_ws;
    bf16_t* wb = xb + (size_t)M * K;

    int n8x = (M * K) / 8;
    int n8w = (N * K) / 8;
    cvt_x_kernel<<<2048, 256, 0, stream>>>(x, xb, n8x);
    cvt_w_kernel<<<2048, 256, 0, stream>>>(w, sc, wb, K / 8, n8w);

    dim3 grid((M / BM) * (N / BN));
    gemm_bt_bf16<<<grid, 256, 0, stream>>>(xb, wb, bias, out, M, N, K);
  } else {
    int total = M * N;
    fallback_gemm<<<(total + 255) / 256, 256, 0, stream>>>(x, w, sc, bias, out,
                                                           M, N, K);
  }
}

// Round 2
// 167.501 us; speedup vs baseline: 1.3855x; 1.3855x over previous
//
#include <hip/hip_runtime.h>
#include <hip/hip_bf16.h>
#include <stdint.h>

typedef __bf16 bf16_t;
typedef bf16_t bf16x8 __attribute__((ext_vector_type(8)));
typedef float f32x4 __attribute__((ext_vector_type(4)));

#define BM 256
#define BN 256
#define BK 64

// ---------------------------------------------------------------------------
// async global->LDS 16B copy. LDS dest is wave-uniform base; HW adds lane*16.
// Global source IS per-lane -> swizzled LDS content via pre-swizzled source.
// ---------------------------------------------------------------------------
__device__ __forceinline__ void gload_lds16(const void* g, void* l) {
  __builtin_amdgcn_global_load_lds(
      (const __attribute__((address_space(1))) uint32_t*)g,
      (__attribute__((address_space(3))) uint32_t*)l, 16, 0, 0);
}

// ---------------------------------------------------------------------------
// fp32 -> bf16 conversion (x), vectorized 8 elems/thread, grid-stride
// ---------------------------------------------------------------------------
__global__ __launch_bounds__(256) void cvt_x_kernel(
    const float* __restrict__ in, bf16_t* __restrict__ out, int n8) {
  int stride = gridDim.x * blockDim.x;
  for (int i = blockIdx.x * blockDim.x + threadIdx.x; i < n8; i += stride) {
    const f32x4* p = (const f32x4*)in + 2 * (size_t)i;
    f32x4 a = p[0], b = p[1];
    bf16x8 o;
#pragma unroll
    for (int r = 0; r < 4; ++r) { o[r] = (bf16_t)a[r]; o[r + 4] = (bf16_t)b[r]; }
    *((bf16x8*)out + i) = o;
  }
}

// fp32 weight -> bf16 with per-row (output channel) scale folded in
__global__ __launch_bounds__(256) void cvt_w_kernel(
    const float* __restrict__ in, const float* __restrict__ scale,
    bf16_t* __restrict__ out, int k8, int n8) {
  int stride = gridDim.x * blockDim.x;
  for (int i = blockIdx.x * blockDim.x + threadIdx.x; i < n8; i += stride) {
    int row = i / k8;
    float s = scale[row];
    const f32x4* p = (const f32x4*)in + 2 * (size_t)i;
    f32x4 a = p[0], b = p[1];
    bf16x8 o;
#pragma unroll
    for (int r = 0; r < 4; ++r) {
      o[r] = (bf16_t)(a[r] * s);
      o[r + 4] = (bf16_t)(b[r] * s);
    }
    *((bf16x8*)out + i) = o;
  }
}

// ---------------------------------------------------------------------------
// 256x256 8-phase bf16 GEMM, both operands K-major (B^T form).
// 8 waves (2M x 4N), per-wave output 128x64. BK=64 split into two K=32
// half-units per matrix -> 4 units/K-tile of 16KB each (256 rows x 64B).
// LDS = 2 buffers x 4 units = 128KB. Ring: each phase stages ONE unit into
// a region freed >=2 phases earlier; ONE counted vmcnt(4) per K-tile.
// Chunk-XOR swizzle (c ^= row&3, 16B granularity) on both the staged global
// source and the ds_read address (same involution).
// ---------------------------------------------------------------------------
__global__ __launch_bounds__(512, 2) void gemm256(
    const bf16_t* __restrict__ A, const bf16_t* __restrict__ B,
    const float* __restrict__ bias, float* __restrict__ C,
    int M, int N, int K) {
  __shared__ __attribute__((aligned(16))) char lds[131072];

  const int tid = threadIdx.x;
  const int lane = tid & 63;
  const int wave = tid >> 6;
  const int wm = wave >> 2;   // 0..1  (row half of tile)
  const int wn = wave & 3;    // 0..3  (col quarter of tile)

  // XCD-aware bijective swizzle (grid multiple of 8 at 4096^2 / 256^2)
  int nwg = gridDim.x;
  int wg = blockIdx.x;
  if ((nwg & 7) == 0) { int cpx = nwg >> 3; wg = (wg & 7) * cpx + (wg >> 3); }
  const int ntn = N / BN;
  const int tm = wg / ntn;
  const int tn = wg % ntn;

  const size_t Kb = (size_t)K * 2;
  const char* gApan = (const char*)A + (size_t)tm * BM * Kb;
  const char* gBpan = (const char*)B + (size_t)tn * BN * Kb;

  // ---- ds_read offsets within a 16KB unit (row*64 + swizzled 16B chunk) ----
  const int xc = (((lane >> 4) ^ (lane & 3)) << 4);
  int aoff[2][4], boff[4];
#pragma unroll
  for (int ch = 0; ch < 2; ++ch)
#pragma unroll
    for (int i = 0; i < 4; ++i) {
      int row = wm * 128 + ch * 64 + i * 16 + (lane & 15);
      aoff[ch][i] = row * 64 + xc;
    }
#pragma unroll
  for (int j = 0; j < 4; ++j) {
    int row = wn * 64 + j * 16 + (lane & 15);
    boff[j] = row * 64 + xc;
  }

  // ---- staging offsets: wave w covers rows [(2w+s)*16, +16) of a unit ----
  // LDS linear dest; global source pre-swizzled with the same chunk XOR.
  size_t srcoff[2];
  int ldst[2];
#pragma unroll
  for (int s = 0; s < 2; ++s) {
    int r = (wave * 2 + s) * 16 + (lane >> 2);
    int c = (lane & 3) ^ (r & 3);
    srcoff[s] = (size_t)r * Kb + (size_t)(c << 4);
    ldst[s] = (wave * 2 + s) * 1024;
  }

#define STAGE_U(dstbase, pan, kbyte)                                          \
  {                                                                           \
    gload_lds16((pan) + srcoff[0] + (size_t)(kbyte), lds + (dstbase) + ldst[0]); \
    gload_lds16((pan) + srcoff[1] + (size_t)(kbyte), lds + (dstbase) + ldst[1]); \
  }

  f32x4 acc[8][4];
#pragma unroll
  for (int a = 0; a < 8; ++a)
#pragma unroll
    for (int j = 0; j < 4; ++j) acc[a][j] = (f32x4)0.0f;

  const int NT = K / BK;

  // ---- prologue: tile0 all 4 units + tile1 K0 units; leave 2 in flight ----
  STAGE_U(0,             gApan, 0);    // A-K0 t0 -> (buf0,A,0)
  STAGE_U(32768,         gBpan, 0);    // B-K0 t0
  STAGE_U(16384,         gApan, 64);   // A-K1 t0
  STAGE_U(49152,         gBpan, 64);   // B-K1 t0
  if (NT > 1) {
    STAGE_U(65536,         gApan, 128);  // A-K0 t1 -> (buf1,A,0)
    STAGE_U(65536 + 32768, gBpan, 128);  // B-K0 t1
    asm volatile("s_waitcnt vmcnt(4)" ::: "memory");  // t0 fully landed
  } else {
    asm volatile("s_waitcnt vmcnt(0)" ::: "memory");
  }
  __builtin_amdgcn_s_barrier();

  for (int t = 0; t < NT; ++t) {
    const int bb = (t & 1) << 16;
    const int nb = bb ^ 65536;
    const size_t kb1 = (size_t)(t + 1) * 128;
    const size_t kb2 = (size_t)(t + 2) * 128;
    const bool st1 = (t + 1) < NT;
    const bool st2 = (t + 2) < NT;

    const char* lA0 = lds + bb;
    const char* lA1 = lds + bb + 16384;
    const char* lB0 = lds + bb + 32768;
    const char* lB1 = lds + bb + 49152;

    bf16x8 af[4], bf0[4], bf1[4];

    // ---------------- P1: C-half0 x K-half0 ----------------
#pragma unroll
    for (int i = 0; i < 4; ++i) af[i] = *(const bf16x8*)(lA0 + aoff[0][i]);
#pragma unroll
    for (int j = 0; j < 4; ++j) bf0[j] = *(const bf16x8*)(lB0 + boff[j]);
    if (st1) STAGE_U(nb + 16384, gApan, kb1 + 64);   // A-K1(t+1)
    __builtin_amdgcn_s_barrier();
    asm volatile("s_waitcnt lgkmcnt(0)" ::: "memory");
    __builtin_amdgcn_s_setprio(1);
#pragma unroll
    for (int i = 0; i < 4; ++i)
#pragma unroll
      for (int j = 0; j < 4; ++j)
        acc[i][j] = __builtin_amdgcn_mfma_f32_16x16x32_bf16(af[i], bf0[j],
                                                            acc[i][j], 0, 0, 0);
    __builtin_amdgcn_s_setprio(0);
    __builtin_amdgcn_s_barrier();

    // ---------------- P2: C-half1 x K-half0 (reuse bf0) ----------------
#pragma unroll
    for (int i = 0; i < 4; ++i) af[i] = *(const bf16x8*)(lA0 + aoff[1][i]);
    if (st1) STAGE_U(nb + 49152, gBpan, kb1 + 64);   // B-K1(t+1)
    __builtin_amdgcn_s_barrier();
    asm volatile("s_waitcnt lgkmcnt(0)" ::: "memory");
    __builtin_amdgcn_s_setprio(1);
#pragma unroll
    for (int i = 0; i < 4; ++i)
#pragma unroll
      for (int j = 0; j < 4; ++j)
        acc[4 + i][j] = __builtin_amdgcn_mfma_f32_16x16x32_bf16(
            af[i], bf0[j], acc[4 + i][j], 0, 0, 0);
    __builtin_amdgcn_s_setprio(0);
    __builtin_amdgcn_s_barrier();

    // ---------------- P3: C-half0 x K-half1 ----------------
#pragma unroll
    for (int i = 0; i < 4; ++i) af[i] = *(const bf16x8*)(lA1 + aoff[0][i]);
#pragma unroll
    for (int j = 0; j < 4; ++j) bf1[j] = *(const bf16x8*)(lB1 + boff[j]);
    if (st2) STAGE_U(bb, gApan, kb2);                // A-K0(t+2), region freed at P2
    __builtin_amdgcn_s_barrier();
    asm volatile("s_waitcnt lgkmcnt(0)" ::: "memory");
    __builtin_amdgcn_s_setprio(1);
#pragma unroll
    for (int i = 0; i < 4; ++i)
#pragma unroll
      for (int j = 0; j < 4; ++j)
        acc[i][j] = __builtin_amdgcn_mfma_f32_16x16x32_bf16(af[i], bf1[j],
                                                            acc[i][j], 0, 0, 0);
    __builtin_amdgcn_s_setprio(0);
    __builtin_amdgcn_s_barrier();

    // ---------------- P4: C-half1 x K-half1 (reuse bf1) ----------------
#pragma unroll
    for (int i = 0; i < 4; ++i) af[i] = *(const bf16x8*)(lA1 + aoff[1][i]);
    if (st2) STAGE_U(bb + 32768, gBpan, kb2);        // B-K0(t+2)
    __builtin_amdgcn_s_barrier();
    asm volatile("s_waitcnt lgkmcnt(0)" ::: "memory");
    __builtin_amdgcn_s_setprio(1);
#pragma unroll
    for (int i = 0; i < 4; ++i)
#pragma unroll
      for (int j = 0; j < 4; ++j)
        acc[4 + i][j] = __builtin_amdgcn_mfma_f32_16x16x32_bf16(
            af[i], bf1[j], acc[4 + i][j], 0, 0, 0);
    __builtin_amdgcn_s_setprio(0);
    // counted wait: allow the 2 newest units (P3/P4 stages) to stay in flight
    if (st2)      asm volatile("s_waitcnt vmcnt(4)" ::: "memory");
    else if (st1) asm volatile("s_waitcnt vmcnt(0)" ::: "memory");
    __builtin_amdgcn_s_barrier();
  }
#undef STAGE_U

  // ---- epilogue: bias + store. C/D: col=lane&15, row=(lane>>4)*4+r ----
  const int row0 = tm * BM + wm * 128;
  const int col0 = tn * BN + wn * 64;
#pragma unroll
  for (int j = 0; j < 4; ++j) {
    int c = col0 + j * 16 + (lane & 15);
    float bv = bias[c];
#pragma unroll
    for (int a = 0; a < 8; ++a) {
      int ch = a >> 2, i = a & 3;
      int rbase = row0 + ch * 64 + i * 16 + ((lane >> 4) << 2);
#pragma unroll
      for (int r = 0; r < 4; ++r)
        C[(size_t)(rbase + r) * N + c] = acc[a][j][r] + bv;
    }
  }
}

// ---------------------------------------------------------------------------
// fallback: naive fp32 (only if workspace/shape unsuitable — correctness net)
// ---------------------------------------------------------------------------
__global__ void fallback_gemm(const float* __restrict__ x,
                              const float* __restrict__ w,
                              const float* __restrict__ s,
                              const float* __restrict__ b,
                              float* __restrict__ out, int M, int N, int K) {
  int o = blockIdx.x * blockDim.x + threadIdx.x;
  if (o >= M * N) return;
  int m = o / N, n = o % N;
  const float* xr = x + (size_t)m * K;
  const float* wr = w + (size_t)n * K;
  float acc = 0.f;
  for (int k = 0; k < K; ++k) acc += xr[k] * wr[k];
  out[o] = acc * s[n] + b[n];
}

extern "C" void kernel_launch(void* const* d_in, const int* in_sizes, int n_in,
                              void* d_out, int out_size, void* d_ws,
                              size_t ws_size, hipStream_t stream) {
  const float* x = (const float*)d_in[0];
  const float* w = (const float*)d_in[1];
  const float* sc = (const float*)d_in[2];
  const float* bias = (const float*)d_in[3];
  float* out = (float*)d_out;

  const int N = in_sizes[2];        // out_features (weight_scale length)
  const int K = in_sizes[1] / N;    // in_features
  const int M = in_sizes[0] / K;    // tokens

  const size_t need = ((size_t)M * K + (size_t)N * K) * sizeof(bf16_t);
  const bool fast = (ws_size >= need) && (M % BM == 0) && (N % BN == 0) &&
                    (K % BK == 0) && (K / BK >= 1);

  if (fast) {
    bf16_t* xb = (bf16_t*)d_ws;
    bf16_t* wb = xb + (size_t)M * K;

    int n8x = (M * K) / 8;
    int n8w = (N * K) / 8;
    cvt_x_kernel<<<2048, 256, 0, stream>>>(x, xb, n8x);
    cvt_w_kernel<<<2048, 256, 0, stream>>>(w, sc, wb, K / 8, n8w);

    dim3 grid((M / BM) * (N / BN));
    gemm256<<<grid, 512, 0, stream>>>(xb, wb, bias, out, M, N, K);
  } else {
    int total = M * N;
    fallback_gemm<<<(total + 255) / 256, 256, 0, stream>>>(x, w, sc, bias, out,
                                                           M, N, K);
  }
}

// Round 3
// 159.580 us; speedup vs baseline: 1.4543x; 1.0496x over previous
//
#include <hip/hip_runtime.h>
#include <hip/hip_bf16.h>
#include <stdint.h>

typedef __bf16 bf16_t;
typedef bf16_t bf16x8 __attribute__((ext_vector_type(8)));
typedef float f32x4 __attribute__((ext_vector_type(4)));

#define BM 256
#define BN 256
#define BK 64

// ---------------------------------------------------------------------------
// async global->LDS 16B copy. LDS dest is wave-uniform base; HW adds lane*16.
// Global source IS per-lane -> swizzled LDS content via pre-swizzled source.
// ---------------------------------------------------------------------------
__device__ __forceinline__ void gload_lds16(const void* g, void* l) {
  __builtin_amdgcn_global_load_lds(
      (const __attribute__((address_space(1))) uint32_t*)g,
      (__attribute__((address_space(3))) uint32_t*)l, 16, 0, 0);
}

// ---------------------------------------------------------------------------
// fused fp32->bf16 conversion: blocks [0,gx) convert x, [gx,gx+gw) convert
// weight (per-out-channel scale folded in). 8 elems/thread, grid-stride.
// ---------------------------------------------------------------------------
__global__ __launch_bounds__(256) void cvt_kernel(
    const float* __restrict__ x, bf16_t* __restrict__ xo, int n8x,
    const float* __restrict__ w, const float* __restrict__ scale,
    bf16_t* __restrict__ wo, int k8, int n8w, int gx) {
  if ((int)blockIdx.x < gx) {
    int stride = gx * blockDim.x;
    for (int i = blockIdx.x * blockDim.x + threadIdx.x; i < n8x; i += stride) {
      const f32x4* p = (const f32x4*)x + 2 * (size_t)i;
      f32x4 a = p[0], b = p[1];
      bf16x8 o;
#pragma unroll
      for (int r = 0; r < 4; ++r) { o[r] = (bf16_t)a[r]; o[r + 4] = (bf16_t)b[r]; }
      *((bf16x8*)xo + i) = o;
    }
  } else {
    int stride = (gridDim.x - gx) * blockDim.x;
    for (int i = (blockIdx.x - gx) * blockDim.x + threadIdx.x; i < n8w;
         i += stride) {
      int row = i / k8;
      float s = scale[row];
      const f32x4* p = (const f32x4*)w + 2 * (size_t)i;
      f32x4 a = p[0], b = p[1];
      bf16x8 o;
#pragma unroll
      for (int r = 0; r < 4; ++r) {
        o[r] = (bf16_t)(a[r] * s);
        o[r + 4] = (bf16_t)(b[r] * s);
      }
      *((bf16x8*)wo + i) = o;
    }
  }
}

// ---------------------------------------------------------------------------
// 256x256 8-phase bf16 GEMM, both operands K-major (B^T form).
// 8 waves (2M x 4N), per-wave output 128x64. BK=64 split into two K=32
// half-units per matrix -> 4 units/K-tile of 16KB each (256 rows x 64B).
// LDS = 2 buffers x 4 units = 128KB. Ring: each phase stages ONE unit into
// a region freed >=2 phases earlier; ONE counted vmcnt(4) per K-tile.
//
// LDS swizzle: chunk-XOR with s(row) = (row>>1)&3 at 16B granularity.
//   bank phase of (row, chunk) = (16*(row&1) + 4*chunk) mod 32; with
//   c_read = (lane>>4) ^ ((lane>>1)&3) every 8-consecutive-lane group covers
//   all 32 banks exactly once -> conflict-free ds_read_b128.
//   Staging pre-applies the same involution on the global source
//   (c_src = (lane&3) ^ ((lane>>3)&3)); LDS dest stays linear (HW requires).
// ---------------------------------------------------------------------------
__global__ __launch_bounds__(512, 2) void gemm256(
    const bf16_t* __restrict__ A, const bf16_t* __restrict__ B,
    const float* __restrict__ bias, float* __restrict__ C,
    int M, int N, int K) {
  __shared__ __attribute__((aligned(16))) char lds[131072];

  const int tid = threadIdx.x;
  const int lane = tid & 63;
  const int wave = tid >> 6;
  const int wm = wave >> 2;   // 0..1  (row half of tile)
  const int wn = wave & 3;    // 0..3  (col quarter of tile)

  // XCD-aware bijective swizzle (grid multiple of 8 at 4096^2 / 256^2)
  int nwg = gridDim.x;
  int wg = blockIdx.x;
  if ((nwg & 7) == 0) { int cpx = nwg >> 3; wg = (wg & 7) * cpx + (wg >> 3); }
  const int ntn = N / BN;
  const int tm = wg / ntn;
  const int tn = wg % ntn;

  const size_t Kb = (size_t)K * 2;
  const char* gApan = (const char*)A + (size_t)tm * BM * Kb;
  const char* gBpan = (const char*)B + (size_t)tn * BN * Kb;

  // ---- ds_read offsets within a 16KB unit (row*64 + swizzled 16B chunk) ----
  // row bases are multiples of 16 -> (row>>1)&3 == (lane>>1)&3.
  const int xc = (((lane >> 4) ^ ((lane >> 1) & 3)) << 4);
  int aoff[2][4], boff[4];
#pragma unroll
  for (int ch = 0; ch < 2; ++ch)
#pragma unroll
    for (int i = 0; i < 4; ++i) {
      int row = wm * 128 + ch * 64 + i * 16 + (lane & 15);
      aoff[ch][i] = row * 64 + xc;
    }
#pragma unroll
  for (int j = 0; j < 4; ++j) {
    int row = wn * 64 + j * 16 + (lane & 15);
    boff[j] = row * 64 + xc;
  }

  // ---- staging offsets: wave w covers rows [(2w+s)*16, +16) of a unit ----
  // staged row r = base16 + (lane>>2) -> (r>>1)&3 == (lane>>3)&3.
  size_t srcoff[2];
  int ldst[2];
#pragma unroll
  for (int s = 0; s < 2; ++s) {
    int r = (wave * 2 + s) * 16 + (lane >> 2);
    int c = (lane & 3) ^ ((lane >> 3) & 3);
    srcoff[s] = (size_t)r * Kb + (size_t)(c << 4);
    ldst[s] = (wave * 2 + s) * 1024;
  }

#define STAGE_U(dstbase, pan, kbyte)                                          \
  {                                                                           \
    gload_lds16((pan) + srcoff[0] + (size_t)(kbyte), lds + (dstbase) + ldst[0]); \
    gload_lds16((pan) + srcoff[1] + (size_t)(kbyte), lds + (dstbase) + ldst[1]); \
  }

  f32x4 acc[8][4];
#pragma unroll
  for (int a = 0; a < 8; ++a)
#pragma unroll
    for (int j = 0; j < 4; ++j) acc[a][j] = (f32x4)0.0f;

  const int NT = K / BK;

  // ---- prologue: tile0 all 4 units + tile1 K0 units; leave 2 in flight ----
  STAGE_U(0,             gApan, 0);    // A-K0 t0 -> (buf0,A,0)
  STAGE_U(32768,         gBpan, 0);    // B-K0 t0
  STAGE_U(16384,         gApan, 64);   // A-K1 t0
  STAGE_U(49152,         gBpan, 64);   // B-K1 t0
  if (NT > 1) {
    STAGE_U(65536,         gApan, 128);  // A-K0 t1 -> (buf1,A,0)
    STAGE_U(65536 + 32768, gBpan, 128);  // B-K0 t1
    asm volatile("s_waitcnt vmcnt(4)" ::: "memory");  // t0 fully landed
  } else {
    asm volatile("s_waitcnt vmcnt(0)" ::: "memory");
  }
  __builtin_amdgcn_s_barrier();

  for (int t = 0; t < NT; ++t) {
    const int bb = (t & 1) << 16;
    const int nb = bb ^ 65536;
    const size_t kb1 = (size_t)(t + 1) * 128;
    const size_t kb2 = (size_t)(t + 2) * 128;
    const bool st1 = (t + 1) < NT;
    const bool st2 = (t + 2) < NT;

    const char* lA0 = lds + bb;
    const char* lA1 = lds + bb + 16384;
    const char* lB0 = lds + bb + 32768;
    const char* lB1 = lds + bb + 49152;

    bf16x8 af[4], bf0[4], bf1[4];

    // ---------------- P1: C-half0 x K-half0 ----------------
#pragma unroll
    for (int i = 0; i < 4; ++i) af[i] = *(const bf16x8*)(lA0 + aoff[0][i]);
#pragma unroll
    for (int j = 0; j < 4; ++j) bf0[j] = *(const bf16x8*)(lB0 + boff[j]);
    if (st1) STAGE_U(nb + 16384, gApan, kb1 + 64);   // A-K1(t+1)
    __builtin_amdgcn_s_barrier();
    asm volatile("s_waitcnt lgkmcnt(0)" ::: "memory");
    __builtin_amdgcn_s_setprio(1);
#pragma unroll
    for (int i = 0; i < 4; ++i)
#pragma unroll
      for (int j = 0; j < 4; ++j)
        acc[i][j] = __builtin_amdgcn_mfma_f32_16x16x32_bf16(af[i], bf0[j],
                                                            acc[i][j], 0, 0, 0);
    __builtin_amdgcn_s_setprio(0);
    __builtin_amdgcn_s_barrier();

    // ---------------- P2: C-half1 x K-half0 (reuse bf0) ----------------
#pragma unroll
    for (int i = 0; i < 4; ++i) af[i] = *(const bf16x8*)(lA0 + aoff[1][i]);
    if (st1) STAGE_U(nb + 49152, gBpan, kb1 + 64);   // B-K1(t+1)
    __builtin_amdgcn_s_barrier();
    asm volatile("s_waitcnt lgkmcnt(0)" ::: "memory");
    __builtin_amdgcn_s_setprio(1);
#pragma unroll
    for (int i = 0; i < 4; ++i)
#pragma unroll
      for (int j = 0; j < 4; ++j)
        acc[4 + i][j] = __builtin_amdgcn_mfma_f32_16x16x32_bf16(
            af[i], bf0[j], acc[4 + i][j], 0, 0, 0);
    __builtin_amdgcn_s_setprio(0);
    __builtin_amdgcn_s_barrier();

    // ---------------- P3: C-half0 x K-half1 ----------------
#pragma unroll
    for (int i = 0; i < 4; ++i) af[i] = *(const bf16x8*)(lA1 + aoff[0][i]);
#pragma unroll
    for (int j = 0; j < 4; ++j) bf1[j] = *(const bf16x8*)(lB1 + boff[j]);
    if (st2) STAGE_U(bb, gApan, kb2);                // A-K0(t+2), region freed at P2
    __builtin_amdgcn_s_barrier();
    asm volatile("s_waitcnt lgkmcnt(0)" ::: "memory");
    __builtin_amdgcn_s_setprio(1);
#pragma unroll
    for (int i = 0; i < 4; ++i)
#pragma unroll
      for (int j = 0; j < 4; ++j)
        acc[i][j] = __builtin_amdgcn_mfma_f32_16x16x32_bf16(af[i], bf1[j],
                                                            acc[i][j], 0, 0, 0);
    __builtin_amdgcn_s_setprio(0);
    __builtin_amdgcn_s_barrier();

    // ---------------- P4: C-half1 x K-half1 (reuse bf1) ----------------
#pragma unroll
    for (int i = 0; i < 4; ++i) af[i] = *(const bf16x8*)(lA1 + aoff[1][i]);
    if (st2) STAGE_U(bb + 32768, gBpan, kb2);        // B-K0(t+2)
    __builtin_amdgcn_s_barrier();
    asm volatile("s_waitcnt lgkmcnt(0)" ::: "memory");
    __builtin_amdgcn_s_setprio(1);
#pragma unroll
    for (int i = 0; i < 4; ++i)
#pragma unroll
      for (int j = 0; j < 4; ++j)
        acc[4 + i][j] = __builtin_amdgcn_mfma_f32_16x16x32_bf16(
            af[i], bf1[j], acc[4 + i][j], 0, 0, 0);
    __builtin_amdgcn_s_setprio(0);
    // counted wait: allow the 2 newest units (P3/P4 stages) to stay in flight
    if (st2)      asm volatile("s_waitcnt vmcnt(4)" ::: "memory");
    else if (st1) asm volatile("s_waitcnt vmcnt(0)" ::: "memory");
    __builtin_amdgcn_s_barrier();
  }
#undef STAGE_U

  // ---- epilogue: bias + store. C/D: col=lane&15, row=(lane>>4)*4+r ----
  const int row0 = tm * BM + wm * 128;
  const int col0 = tn * BN + wn * 64;
#pragma unroll
  for (int j = 0; j < 4; ++j) {
    int c = col0 + j * 16 + (lane & 15);
    float bv = bias[c];
#pragma unroll
    for (int a = 0; a < 8; ++a) {
      int ch = a >> 2, i = a & 3;
      int rbase = row0 + ch * 64 + i * 16 + ((lane >> 4) << 2);
#pragma unroll
      for (int r = 0; r < 4; ++r)
        C[(size_t)(rbase + r) * N + c] = acc[a][j][r] + bv;
    }
  }
}

// ---------------------------------------------------------------------------
// fallback: naive fp32 (only if workspace/shape unsuitable — correctness net)
// ---------------------------------------------------------------------------
__global__ void fallback_gemm(const float* __restrict__ x,
                              const float* __restrict__ w,
                              const float* __restrict__ s,
                              const float* __restrict__ b,
                              float* __restrict__ out, int M, int N, int K) {
  int o = blockIdx.x * blockDim.x + threadIdx.x;
  if (o >= M * N) return;
  int m = o / N, n = o % N;
  const float* xr = x + (size_t)m * K;
  const float* wr = w + (size_t)n * K;
  float acc = 0.f;
  for (int k = 0; k < K; ++k) acc += xr[k] * wr[k];
  out[o] = acc * s[n] + b[n];
}

extern "C" void kernel_launch(void* const* d_in, const int* in_sizes, int n_in,
                              void* d_out, int out_size, void* d_ws,
                              size_t ws_size, hipStream_t stream) {
  const float* x = (const float*)d_in[0];
  const float* w = (const float*)d_in[1];
  const float* sc = (const float*)d_in[2];
  const float* bias = (const float*)d_in[3];
  float* out = (float*)d_out;

  const int N = in_sizes[2];        // out_features (weight_scale length)
  const int K = in_sizes[1] / N;    // in_features
  const int M = in_sizes[0] / K;    // tokens

  const size_t need = ((size_t)M * K + (size_t)N * K) * sizeof(bf16_t);
  const bool fast = (ws_size >= need) && (M % BM == 0) && (N % BN == 0) &&
                    (K % BK == 0) && (K / BK >= 1);

  if (fast) {
    bf16_t* xb = (bf16_t*)d_ws;
    bf16_t* wb = xb + (size_t)M * K;

    int n8x = (M * K) / 8;
    int n8w = (N * K) / 8;
    const int gx = 2048;
    cvt_kernel<<<gx + 2048, 256, 0, stream>>>(x, xb, n8x, w, sc, wb, K / 8,
                                              n8w, gx);

    dim3 grid((M / BM) * (N / BN));
    gemm256<<<grid, 512, 0, stream>>>(xb, wb, bias, out, M, N, K);
  } else {
    int total = M * N;
    fallback_gemm<<<(total + 255) / 256, 256, 0, stream>>>(x, w, sc, bias, out,
                                                           M, N, K);
  }
}

// Round 4
// 155.415 us; speedup vs baseline: 1.4933x; 1.0268x over previous
//
#include <hip/hip_runtime.h>
#include <hip/hip_bf16.h>
#include <stdint.h>

typedef __bf16 bf16_t;
typedef bf16_t bf16x8 __attribute__((ext_vector_type(8)));
typedef float f32x4 __attribute__((ext_vector_type(4)));

#define BM 256
#define BN 256
#define BK 64

// ---------------------------------------------------------------------------
// async global->LDS 16B copy. LDS dest is wave-uniform base; HW adds lane*16.
// Global source IS per-lane -> swizzled LDS content via pre-swizzled source.
// ---------------------------------------------------------------------------
__device__ __forceinline__ void gload_lds16(const void* g, void* l) {
  __builtin_amdgcn_global_load_lds(
      (const __attribute__((address_space(1))) uint32_t*)g,
      (__attribute__((address_space(3))) uint32_t*)l, 16, 0, 0);
}

// ---------------------------------------------------------------------------
// fused fp32->bf16 conversion: blocks [0,gx) convert x, [gx,..) convert
// weight (per-out-channel scale folded in). 8 elems/thread, grid-stride.
// ---------------------------------------------------------------------------
__global__ __launch_bounds__(256) void cvt_kernel(
    const float* __restrict__ x, bf16_t* __restrict__ xo, int n8x,
    const float* __restrict__ w, const float* __restrict__ scale,
    bf16_t* __restrict__ wo, int k8, int n8w, int gx) {
  if ((int)blockIdx.x < gx) {
    int stride = gx * blockDim.x;
    for (int i = blockIdx.x * blockDim.x + threadIdx.x; i < n8x; i += stride) {
      const f32x4* p = (const f32x4*)x + 2 * (size_t)i;
      f32x4 a = p[0], b = p[1];
      bf16x8 o;
#pragma unroll
      for (int r = 0; r < 4; ++r) { o[r] = (bf16_t)a[r]; o[r + 4] = (bf16_t)b[r]; }
      *((bf16x8*)xo + i) = o;
    }
  } else {
    int stride = (gridDim.x - gx) * blockDim.x;
    for (int i = (blockIdx.x - gx) * blockDim.x + threadIdx.x; i < n8w;
         i += stride) {
      int row = i / k8;
      float s = scale[row];
      const f32x4* p = (const f32x4*)w + 2 * (size_t)i;
      f32x4 a = p[0], b = p[1];
      bf16x8 o;
#pragma unroll
      for (int r = 0; r < 4; ++r) {
        o[r] = (bf16_t)(a[r] * s);
        o[r + 4] = (bf16_t)(b[r] * s);
      }
      *((bf16x8*)wo + i) = o;
    }
  }
}

// ---------------------------------------------------------------------------
// 256x256 bf16 GEMM, both K-major. 8 waves (2Mx4N), per-wave out 128x64.
// 4 phases/K-tile, ONE barrier per phase. Register prefetch pipeline:
// each phase issues the NEXT phase's ds_reads, then a counted lgkmcnt lets
// its own MFMA start while the LDS services the prefetch. Counted vmcnt(6)
// at P3 / vmcnt(4) at P4 keep 2-3 staged units in flight across barriers.
//
// Hazard ledger (steady state, per K-tile t; buffers bb=t&1, nb=!bb):
//   stage issue:  P1: A-K1(t+1)->nb  P2: B-K1(t+1)->nb
//                 P3: A-K0(t+2)->bb  P4: B-K0(t+2)->bb
//   read issue:   P1: aY(ch1,K0,bb)      P2: aX(ch0,K1,bb)+b1(K1,bb)
//                 P3: aY(ch1,K1,bb)      P4: aX(ch0,K0,nb)+b0(K0,nb)
//   vmcnt(6)@P3 drains B-K0(t+1) (+older)  -> P4's nb reads safe after bar.
//   vmcnt(4)@P4 drains A/B-K1(t+1)         -> P2(t+1)'s reads safe after bar.
//   every region's re-stage is >= 1 barrier after its last read's lgkmcnt.
//
// LDS swizzle: chunk-XOR s(row)=(row>>1)&3 at 16B granularity (conflict-free,
// verified 0 SQ_LDS_BANK_CONFLICT); staging pre-applies it on the global src.
// ---------------------------------------------------------------------------
__global__ __launch_bounds__(512, 2) void gemm256(
    const bf16_t* __restrict__ A, const bf16_t* __restrict__ B,
    const float* __restrict__ bias, float* __restrict__ C,
    int M, int N, int K) {
  __shared__ __attribute__((aligned(16))) char lds[131072];

  const int tid = threadIdx.x;
  const int lane = tid & 63;
  const int wave = tid >> 6;
  const int wm = wave >> 2;   // 0..1  (row half of tile)
  const int wn = wave & 3;    // 0..3  (col quarter of tile)

  // XCD-aware bijective swizzle
  int nwg = gridDim.x;
  int wg = blockIdx.x;
  if ((nwg & 7) == 0) { int cpx = nwg >> 3; wg = (wg & 7) * cpx + (wg >> 3); }
  const int ntn = N / BN;
  const int tm = wg / ntn;
  const int tn = wg % ntn;

  const size_t Kb = (size_t)K * 2;
  const char* gApan = (const char*)A + (size_t)tm * BM * Kb;
  const char* gBpan = (const char*)B + (size_t)tn * BN * Kb;

  // ---- ds_read offsets within a 16KB unit (row*64 + swizzled 16B chunk) ----
  const int xc = (((lane >> 4) ^ ((lane >> 1) & 3)) << 4);
  int aoff[2][4], boff[4];
#pragma unroll
  for (int ch = 0; ch < 2; ++ch)
#pragma unroll
    for (int i = 0; i < 4; ++i) {
      int row = wm * 128 + ch * 64 + i * 16 + (lane & 15);
      aoff[ch][i] = row * 64 + xc;
    }
#pragma unroll
  for (int j = 0; j < 4; ++j) {
    int row = wn * 64 + j * 16 + (lane & 15);
    boff[j] = row * 64 + xc;
  }

  // ---- staging offsets ----
  size_t srcoff[2];
  int ldst[2];
#pragma unroll
  for (int s = 0; s < 2; ++s) {
    int r = (wave * 2 + s) * 16 + (lane >> 2);
    int c = (lane & 3) ^ ((lane >> 3) & 3);
    srcoff[s] = (size_t)r * Kb + (size_t)(c << 4);
    ldst[s] = (wave * 2 + s) * 1024;
  }

#define STAGE_U(dstbase, pan, kbyte)                                          \
  {                                                                           \
    gload_lds16((pan) + srcoff[0] + (size_t)(kbyte), lds + (dstbase) + ldst[0]); \
    gload_lds16((pan) + srcoff[1] + (size_t)(kbyte), lds + (dstbase) + ldst[1]); \
  }
#define RD_A(dst, base, ch)                                                   \
  _Pragma("unroll") for (int i_ = 0; i_ < 4; ++i_)                            \
      dst[i_] = *(const bf16x8*)((base) + aoff[ch][i_]);
#define RD_B(dst, base)                                                       \
  _Pragma("unroll") for (int j_ = 0; j_ < 4; ++j_)                            \
      dst[j_] = *(const bf16x8*)((base) + boff[j_]);
#define MFMA16(ab, bb_, accbase)                                              \
  __builtin_amdgcn_s_setprio(1);                                              \
  _Pragma("unroll") for (int i_ = 0; i_ < 4; ++i_)                            \
      _Pragma("unroll") for (int j_ = 0; j_ < 4; ++j_)                        \
          acc[(accbase) + i_][j_] = __builtin_amdgcn_mfma_f32_16x16x32_bf16(  \
              ab[i_], bb_[j_], acc[(accbase) + i_][j_], 0, 0, 0);             \
  __builtin_amdgcn_s_setprio(0);
#define WAIT_LGKM(n) asm volatile("s_waitcnt lgkmcnt(" #n ")" ::: "memory")
#define WAIT_VM(n)   asm volatile("s_waitcnt vmcnt(" #n ")" ::: "memory")
#define BAR()        __builtin_amdgcn_s_barrier()

  f32x4 acc[8][4];
#pragma unroll
  for (int a = 0; a < 8; ++a)
#pragma unroll
    for (int j = 0; j < 4; ++j) acc[a][j] = (f32x4)0.0f;

  const int NT = K / BK;

  // ---- prologue: tile0 (4 units) + tile1 K0 (2 units); 2 left in flight ----
  STAGE_U(0,             gApan, 0);
  STAGE_U(32768,         gBpan, 0);
  STAGE_U(16384,         gApan, 64);
  STAGE_U(49152,         gBpan, 64);
  if (NT > 1) {
    STAGE_U(65536,         gApan, 128);
    STAGE_U(65536 + 32768, gBpan, 128);
    WAIT_VM(4);
  } else {
    WAIT_VM(0);
  }
  BAR();

  bf16x8 aX[4], aY[4], b0[4], b1[4];
  RD_A(aX, lds + 0, 0);       // A(ch0,K0) tile0
  RD_B(b0, lds + 32768);      // B-K0 tile0

  for (int t = 0; t < NT; ++t) {
    const int bb = (t & 1) << 16;
    const int nb = bb ^ 65536;
    const size_t kb1 = (size_t)(t + 1) * 128;
    const size_t kb2 = (size_t)(t + 2) * 128;
    const bool st1 = (t + 1) < NT;
    const bool st2 = (t + 2) < NT;

    const char* lA0 = lds + bb;
    const char* lA1 = lds + bb + 16384;
    const char* lB1 = lds + bb + 49152;

    // ---- P1: MFMA(aX=A ch0 K0, b0) ; prefetch aY = A ch1 K0 ----
    RD_A(aY, lA0, 1);
    if (st1) STAGE_U(nb + 16384, gApan, kb1 + 64);   // A-K1(t+1)
    WAIT_LGKM(4);
    MFMA16(aX, b0, 0);
    BAR();

    // ---- P2: MFMA(aY=A ch1 K0, b0) ; prefetch aX = A ch0 K1, b1 = B-K1 ----
    RD_A(aX, lA1, 0);
    RD_B(b1, lB1);
    if (st1) STAGE_U(nb + 49152, gBpan, kb1 + 64);   // B-K1(t+1)
    WAIT_LGKM(8);
    MFMA16(aY, b0, 4);
    BAR();

    // ---- P3: MFMA(aX=A ch0 K1, b1) ; prefetch aY = A ch1 K1 ----
    RD_A(aY, lA1, 1);
    if (st2) STAGE_U(bb, gApan, kb2);                // A-K0(t+2)
    WAIT_LGKM(4);
    MFMA16(aX, b1, 0);
    WAIT_VM(6);   // drains B-K0(t+1): nb K0 regions readable next phase
    BAR();

    // ---- P4: MFMA(aY=A ch1 K1, b1) ; prefetch next tile's aX, b0 ----
    if (st1) {
      RD_A(aX, lds + nb, 0);        // A(ch0,K0) of t+1
      RD_B(b0, lds + nb + 32768);   // B-K0 of t+1
    }
    if (st2) STAGE_U(bb + 32768, gBpan, kb2);        // B-K0(t+2)
    if (st1) { WAIT_LGKM(8); } else { WAIT_LGKM(0); }
    MFMA16(aY, b1, 4);
    WAIT_VM(4);   // drains A/B-K1(t+1): lA1/lB1 readable from P2(t+1)
    BAR();
  }
#undef STAGE_U
#undef RD_A
#undef RD_B
#undef MFMA16
#undef WAIT_LGKM
#undef WAIT_VM
#undef BAR

  // ---- epilogue: bias + store. C/D: col=lane&15, row=(lane>>4)*4+r ----
  const int row0 = tm * BM + wm * 128;
  const int col0 = tn * BN + wn * 64;
#pragma unroll
  for (int j = 0; j < 4; ++j) {
    int c = col0 + j * 16 + (lane & 15);
    float bv = bias[c];
#pragma unroll
    for (int a = 0; a < 8; ++a) {
      int ch = a >> 2, i = a & 3;
      int rbase = row0 + ch * 64 + i * 16 + ((lane >> 4) << 2);
#pragma unroll
      for (int r = 0; r < 4; ++r)
        C[(size_t)(rbase + r) * N + c] = acc[a][j][r] + bv;
    }
  }
}

// ---------------------------------------------------------------------------
// fallback: naive fp32 (only if workspace/shape unsuitable — correctness net)
// ---------------------------------------------------------------------------
__global__ void fallback_gemm(const float* __restrict__ x,
                              const float* __restrict__ w,
                              const float* __restrict__ s,
                              const float* __restrict__ b,
                              float* __restrict__ out, int M, int N, int K) {
  int o = blockIdx.x * blockDim.x + threadIdx.x;
  if (o >= M * N) return;
  int m = o / N, n = o % N;
  const float* xr = x + (size_t)m * K;
  const float* wr = w + (size_t)n * K;
  float acc = 0.f;
  for (int k = 0; k < K; ++k) acc += xr[k] * wr[k];
  out[o] = acc * s[n] + b[n];
}

extern "C" void kernel_launch(void* const* d_in, const int* in_sizes, int n_in,
                              void* d_out, int out_size, void* d_ws,
                              size_t ws_size, hipStream_t stream) {
  const float* x = (const float*)d_in[0];
  const float* w = (const float*)d_in[1];
  const float* sc = (const float*)d_in[2];
  const float* bias = (const float*)d_in[3];
  float* out = (float*)d_out;

  const int N = in_sizes[2];        // out_features (weight_scale length)
  const int K = in_sizes[1] / N;    // in_features
  const int M = in_sizes[0] / K;    // tokens

  const size_t need = ((size_t)M * K + (size_t)N * K) * sizeof(bf16_t);
  const bool fast = (ws_size >= need) && (M % BM == 0) && (N % BN == 0) &&
                    (K % BK == 0) && (K / BK >= 1);

  if (fast) {
    bf16_t* xb = (bf16_t*)d_ws;
    bf16_t* wb = xb + (size_t)M * K;

    int n8x = (M * K) / 8;
    int n8w = (N * K) / 8;
    const int gx = 2048;
    cvt_kernel<<<gx + 2048, 256, 0, stream>>>(x, xb, n8x, w, sc, wb, K / 8,
                                              n8w, gx);

    dim3 grid((M / BM) * (N / BN));
    gemm256<<<grid, 512, 0, stream>>>(xb, wb, bias, out, M, N, K);
  } else {
    int total = M * N;
    fallback_gemm<<<(total + 255) / 256, 256, 0, stream>>>(x, w, sc, bias, out,
                                                           M, N, K);
  }
}